// Round 1
// baseline (36.056 us; speedup 1.0000x reference)
//
#include <hip/hip_runtime.h>
#include <math.h>

#define ROWS 32
#define LROW 15104
#define TWIN 128
#define SSH  257
#define NWIN 118
#define TRIM 14848   // LROW - 2*TWIN

// ---------------- per-row normalization stats ----------------
__global__ void stats_kernel(const float* __restrict__ data,
                             const float* __restrict__ target,
                             float* __restrict__ scale_out) {
    int row = blockIdx.x;
    int tid = threadIdx.x;
    const float* x = data + row * LROW + TWIN;
    const float* r = target + row * LROW + TWIN;
    float sd = 0.f, sd2 = 0.f, sr = 0.f, sr2 = 0.f;
    for (int i = tid; i < TRIM; i += 256) {
        float a = x[i], b = r[i];
        sd += a; sd2 += a * a; sr += b; sr2 += b * b;
    }
    __shared__ float sh[4][256];
    sh[0][tid] = sd; sh[1][tid] = sd2; sh[2][tid] = sr; sh[3][tid] = sr2;
    __syncthreads();
    for (int off = 128; off > 0; off >>= 1) {
        if (tid < off) {
            sh[0][tid] += sh[0][tid + off];
            sh[1][tid] += sh[1][tid + off];
            sh[2][tid] += sh[2][tid + off];
            sh[3][tid] += sh[3][tid + off];
        }
        __syncthreads();
    }
    if (tid == 0) {
        const float inv = 1.0f / (float)TRIM;
        float md = sh[0][0] * inv, mr = sh[2][0] * inv;
        float vx = fmaxf(sh[1][0] * inv - md * md, 0.f);
        float vr = fmaxf(sh[3][0] * inv - mr * mr, 0.f);
        float mag_x = sqrtf(vx), mag_r = sqrtf(vr);
        float mag_min = fminf(mag_x, mag_r);
        float mag_norm = sqrtf(mag_min * mag_r) + 0.001f;
        scale_out[row] = 1.0f / mag_norm;
    }
}

// ---------------- main shifted-L2 loss per (row, window) ----------------
__global__ void loss_kernel(const float* __restrict__ data,
                            const float* __restrict__ target,
                            const float* __restrict__ scale_arr,
                            float* __restrict__ loss_out) {
    int b   = blockIdx.x;
    int row = b / NWIN;
    int n   = b % NWIN;
    int tid = threadIdx.x;

    __shared__ float xs[TWIN];
    __shared__ float ys[3 * TWIN];

    float scale = scale_arr[row];
    const float* xr = data + row * LROW;
    const float* rr = target + row * LROW;
    int base = n * TWIN;

    if (tid < TWIN) xs[tid] = xr[base + tid] * scale;
    for (int j = tid; j < 3 * TWIN; j += 256) {
        int g = base + j - TWIN;   // index into (unpadded) target row
        ys[j] = (g >= 0 && g < LROW) ? rr[g] * scale : 0.f;
    }
    __syncthreads();

    float lmin = 1e30f;
    for (int s = tid; s < SSH; s += 256) {
        float acc = 0.f;
        #pragma unroll 8
        for (int k = 0; k < TWIN; ++k) {
            float d = xs[k] - ys[s + k];
            acc += d * d;
        }
        float mse = acc * (1.0f / (float)TWIN);
        // w[s] = 100 * (1 - blackman(s)),  M = 257
        float ph = (float)s * (float)(M_PI / 128.0);   // 2*pi*s/256
        float bw = 0.42f - 0.5f * cosf(ph) + 0.08f * cosf(2.0f * ph);
        float w  = 100.f * (1.f - bw);
        float loss = (mse + 1.f) * (w + 1.f) - 1.f;
        lmin = fminf(lmin, loss);
    }

    __shared__ float red[256];
    red[tid] = lmin;
    __syncthreads();
    for (int off = 128; off > 0; off >>= 1) {
        if (tid < off) red[tid] = fminf(red[tid], red[tid + off]);
        __syncthreads();
    }
    if (tid == 0) loss_out[b] = red[0];
}

// ---------------- final mean ----------------
__global__ void finish_kernel(const float* __restrict__ loss_in,
                              float* __restrict__ out) {
    int tid = threadIdx.x;
    float s = 0.f;
    for (int i = tid; i < ROWS * NWIN; i += 256) s += loss_in[i];
    __shared__ float sh[256];
    sh[tid] = s;
    __syncthreads();
    for (int off = 128; off > 0; off >>= 1) {
        if (tid < off) sh[tid] += sh[tid + off];
        __syncthreads();
    }
    if (tid == 0) out[0] = sh[0] / (float)(ROWS * NWIN);
}

extern "C" void kernel_launch(void* const* d_in, const int* in_sizes, int n_in,
                              void* d_out, int out_size, void* d_ws, size_t ws_size,
                              hipStream_t stream) {
    const float* data   = (const float*)d_in[0];
    const float* target = (const float*)d_in[1];
    float* scale = (float*)d_ws;
    float* loss  = scale + 64;   // 64-float pad keeps loss array 256B-aligned

    stats_kernel<<<ROWS, 256, 0, stream>>>(data, target, scale);
    loss_kernel<<<ROWS * NWIN, 256, 0, stream>>>(data, target, scale, loss);
    finish_kernel<<<1, 256, 0, stream>>>(loss, (float*)d_out);
}

// Round 2
// 22.255 us; speedup vs baseline: 1.6202x; 1.6202x over previous
//
#include <hip/hip_runtime.h>
#include <math.h>

#define ROWS 32
#define LROW 15104
#define TWIN 128
#define SSH  257
#define NWIN 118
#define TRIM 14848   // LROW - 2*TWIN
#define NW   (ROWS * NWIN)   // 3776 windows

// ---------------- per-row normalization stats ----------------
__global__ void stats_kernel(const float* __restrict__ data,
                             const float* __restrict__ target,
                             float* __restrict__ scale_out) {
    int row = blockIdx.x;
    int tid = threadIdx.x;
    const float4* x4 = (const float4*)(data + row * LROW + TWIN);
    const float4* r4 = (const float4*)(target + row * LROW + TWIN);
    float sd = 0.f, sd2 = 0.f, sr = 0.f, sr2 = 0.f;
    for (int i = tid; i < TRIM / 4; i += 256) {
        float4 a = x4[i], b = r4[i];
        sd  += a.x + a.y + a.z + a.w;
        sd2 += a.x*a.x + a.y*a.y + a.z*a.z + a.w*a.w;
        sr  += b.x + b.y + b.z + b.w;
        sr2 += b.x*b.x + b.y*b.y + b.z*b.z + b.w*b.w;
    }
    __shared__ float sh[4][256];
    sh[0][tid] = sd; sh[1][tid] = sd2; sh[2][tid] = sr; sh[3][tid] = sr2;
    __syncthreads();
    for (int off = 128; off > 0; off >>= 1) {
        if (tid < off) {
            sh[0][tid] += sh[0][tid + off];
            sh[1][tid] += sh[1][tid + off];
            sh[2][tid] += sh[2][tid + off];
            sh[3][tid] += sh[3][tid + off];
        }
        __syncthreads();
    }
    if (tid == 0) {
        const float inv = 1.0f / (float)TRIM;
        float md = sh[0][0] * inv, mr = sh[2][0] * inv;
        float vx = fmaxf(sh[1][0] * inv - md * md, 0.f);
        float vr = fmaxf(sh[3][0] * inv - mr * mr, 0.f);
        float mag_x = sqrtf(vx), mag_r = sqrtf(vr);
        float mag_min = fminf(mag_x, mag_r);
        float mag_norm = sqrtf(mag_min * mag_r) + 0.001f;
        scale_out[row] = 1.0f / mag_norm;
    }
}

// ---------------- main shifted-L2 loss: 1 wave per window, 4 shifts/lane ----
__global__ __launch_bounds__(256) void loss_kernel(
        const float* __restrict__ data,
        const float* __restrict__ target,
        const float* __restrict__ scale_arr,
        float* __restrict__ loss_out) {
    int tid  = threadIdx.x;
    int wave = tid >> 6;
    int lane = tid & 63;
    int widx = blockIdx.x * 4 + wave;       // 944 blocks * 4 = 3776, exact
    int row  = widx / NWIN;
    int n    = widx % NWIN;

    __shared__ float xs[4][TWIN];
    __shared__ float ys[4][3 * TWIN];

    float scale = scale_arr[row];
    const float* xr = data   + row * LROW + n * TWIN;
    const float* rr = target + row * LROW;
    int base = n * TWIN;

    // stage x: 128 floats, 2 per lane (aligned float2)
    {
        float2 v = *(const float2*)(xr + 2 * lane);
        xs[wave][2 * lane]     = v.x * scale;
        xs[wave][2 * lane + 1] = v.y * scale;
    }
    // stage y: 384 floats = 96 float4; 4-aligned window => each float4 fully
    // in-bounds or fully out (zero pad)
    for (int j = lane; j < 96; j += 64) {
        int g0 = base + 4 * j - TWIN;
        float4 v = make_float4(0.f, 0.f, 0.f, 0.f);
        if (g0 >= 0 && g0 < LROW) v = *(const float4*)(rr + g0);
        *(float4*)&ys[wave][4 * j] =
            make_float4(v.x * scale, v.y * scale, v.z * scale, v.w * scale);
    }
    // wave-private LDS region: in-wave dependency, no __syncthreads needed.

    const float4* xs4 = (const float4*)xs[wave];
    const float4* ys4 = (const float4*)ys[wave];

    // shifts s0..s0+3, s0 = 4*lane  (covers s=0..255; s=256 handled below)
    float4 yv0 = ys4[lane];
    float yf0 = yv0.x, yf1 = yv0.y, yf2 = yv0.z;   // y[s0], y[s0+1], y[s0+2]
    float c0 = 0.f, c1 = 0.f, c2 = 0.f, c3 = 0.f;  // cross terms
    float q = 0.f, sx = 0.f;                       // sum y^2 (s0 window), sum x^2

    #pragma unroll
    for (int kb = 0; kb < 32; ++kb) {
        float4 xv  = xs4[kb];              // lane-uniform broadcast
        float4 yv1 = ys4[lane + kb + 1];
        c0 += xv.x*yv0.x + xv.y*yv0.y + xv.z*yv0.z + xv.w*yv0.w;
        c1 += xv.x*yv0.y + xv.y*yv0.z + xv.z*yv0.w + xv.w*yv1.x;
        c2 += xv.x*yv0.z + xv.y*yv0.w + xv.z*yv1.x + xv.w*yv1.y;
        c3 += xv.x*yv0.w + xv.y*yv1.x + xv.z*yv1.y + xv.w*yv1.z;
        q  += yv0.x*yv0.x + yv0.y*yv0.y + yv0.z*yv0.z + yv0.w*yv0.w;
        sx += xv.x*xv.x + xv.y*xv.y + xv.z*xv.z + xv.w*xv.w;
        yv0 = yv1;
    }
    // yv0 now holds y[s0+128 .. s0+131]
    float sy0 = q;
    float sy1 = sy0 - yf0*yf0 + yv0.x*yv0.x;
    float sy2 = sy1 - yf1*yf1 + yv0.y*yv0.y;
    float sy3 = sy2 - yf2*yf2 + yv0.z*yv0.z;

    const float inv = 1.0f / (float)TWIN;
    int   s0  = lane * 4;
    float lmin = 1e30f;
    {
        float mse, ph, cp, bw, w;
        // j = 0
        mse = (sx - 2.f*c0 + sy0) * inv;
        ph  = (float)(s0 + 0) * (float)(M_PI / 128.0);
        cp  = __cosf(ph); bw = 0.42f - 0.5f*cp + 0.08f*(2.f*cp*cp - 1.f);
        w   = 100.f * (1.f - bw);
        lmin = fminf(lmin, (mse + 1.f) * (w + 1.f) - 1.f);
        // j = 1
        mse = (sx - 2.f*c1 + sy1) * inv;
        ph  = (float)(s0 + 1) * (float)(M_PI / 128.0);
        cp  = __cosf(ph); bw = 0.42f - 0.5f*cp + 0.08f*(2.f*cp*cp - 1.f);
        w   = 100.f * (1.f - bw);
        lmin = fminf(lmin, (mse + 1.f) * (w + 1.f) - 1.f);
        // j = 2
        mse = (sx - 2.f*c2 + sy2) * inv;
        ph  = (float)(s0 + 2) * (float)(M_PI / 128.0);
        cp  = __cosf(ph); bw = 0.42f - 0.5f*cp + 0.08f*(2.f*cp*cp - 1.f);
        w   = 100.f * (1.f - bw);
        lmin = fminf(lmin, (mse + 1.f) * (w + 1.f) - 1.f);
        // j = 3
        mse = (sx - 2.f*c3 + sy3) * inv;
        ph  = (float)(s0 + 3) * (float)(M_PI / 128.0);
        cp  = __cosf(ph); bw = 0.42f - 0.5f*cp + 0.08f*(2.f*cp*cp - 1.f);
        w   = 100.f * (1.f - bw);
        lmin = fminf(lmin, (mse + 1.f) * (w + 1.f) - 1.f);
    }

    // s = 256, computed cooperatively: mse = mean_k (x[k] - ys[256+k])^2
    float d1 = xs[wave][lane]      - ys[wave][256 + lane];
    float d2 = xs[wave][lane + 64] - ys[wave][320 + lane];
    float part = d1*d1 + d2*d2;
    for (int off = 32; off > 0; off >>= 1) part += __shfl_down(part, off, 64);
    // wave min-reduce
    for (int off = 32; off > 0; off >>= 1)
        lmin = fminf(lmin, __shfl_down(lmin, off, 64));
    if (lane == 0) {
        float mse256 = part * inv;
        float l256 = (mse256 + 1.f) * 101.f - 1.f;   // w[256] = 100 exactly
        loss_out[widx] = fminf(lmin, l256);
    }
}

// ---------------- final mean ----------------
__global__ void finish_kernel(const float* __restrict__ loss_in,
                              float* __restrict__ out) {
    int tid = threadIdx.x;
    float s = 0.f;
    for (int i = tid; i < NW; i += 256) s += loss_in[i];
    __shared__ float sh[256];
    sh[tid] = s;
    __syncthreads();
    for (int off = 128; off > 0; off >>= 1) {
        if (tid < off) sh[tid] += sh[tid + off];
        __syncthreads();
    }
    if (tid == 0) out[0] = sh[0] / (float)NW;
}

extern "C" void kernel_launch(void* const* d_in, const int* in_sizes, int n_in,
                              void* d_out, int out_size, void* d_ws, size_t ws_size,
                              hipStream_t stream) {
    const float* data   = (const float*)d_in[0];
    const float* target = (const float*)d_in[1];
    float* scale = (float*)d_ws;
    float* loss  = scale + 64;

    stats_kernel<<<ROWS, 256, 0, stream>>>(data, target, scale);
    loss_kernel<<<NW / 4, 256, 0, stream>>>(data, target, scale, loss);
    finish_kernel<<<1, 256, 0, stream>>>(loss, (float*)d_out);
}